// Round 13
// baseline (118.259 us; speedup 1.0000x reference)
//
#include <hip/hip_runtime.h>
#include <hip/hip_bf16.h>

#define N_NODES 50000
#define M_PAD   50048   // 782 * 64
#define N_EDGES 800000
#define NBUCK   391     // bucket = dst>>7 -> 128 nodes per bucket
#define NB_SC   196     // scatter blocks (4096 edges each)
#define NB_CAST5 1563   // ceil(800000/512) cast work items (8 elems each)
#define NB_TR5  224     // ceil(114688/512) transpose items
#define EBMAX   4096    // per-bucket elist capacity (actual max ~2300)
#define MAXSEG  64      // per-(block,bucket) iteration bound (Poisson mean 10.4)

typedef __bf16 bf16x8 __attribute__((ext_vector_type(8)));
typedef float  f32x4  __attribute__((ext_vector_type(4)));

__device__ __forceinline__ ushort f2bf(float f) {
    __hip_bfloat16 h = __float2bfloat16(f);
    return __builtin_bit_cast(ushort, h);
}
__device__ __forceinline__ float bf2f(ushort u) {
    return __builtin_bit_cast(float, (unsigned)u << 16);
}

// async global->LDS, 16B per lane; lds base must be wave-uniform
__device__ __forceinline__ void gload16(const ushort* g, ushort* l) {
    __builtin_amdgcn_global_load_lds(
        (const __attribute__((address_space(1))) unsigned*)g,
        (__attribute__((address_space(3))) unsigned*)l, 16, 0, 0);
}

// ---------------- prep: x cast + weight transpose + compact edge counting-sort ----------------
__device__ __forceinline__ void transpose_one(const float* W, ushort* WT,
                                              int K, int N, int t) {
    int k = t / N, n = t % N;
    WT[n * K + k] = f2bf(W[t]);
}

__global__ __launch_bounds__(512) void k_prep(const float* __restrict__ x,
                                              ushort* __restrict__ xb,
                                              const float* __restrict__ W1, ushort* __restrict__ W1T,
                                              const float* __restrict__ W2, ushort* __restrict__ W2T,
                                              const float* __restrict__ Wc, ushort* __restrict__ WcT,
                                              const int* __restrict__ ei,
                                              int* __restrict__ cnt,
                                              int* __restrict__ ofs,
                                              unsigned* __restrict__ pbuf) {
    int b = blockIdx.x, t = threadIdx.x;
    if (b < NB_CAST5) {
        int i = b * 512 + t;  // 8 elems each
        if (i < N_NODES * 128 / 8) {
            const float4* x4 = (const float4*)x;
            float4 a = x4[(size_t)i * 2], bb = x4[(size_t)i * 2 + 1];
            ushort o[8];
            o[0] = f2bf(a.x); o[1] = f2bf(a.y); o[2] = f2bf(a.z); o[3] = f2bf(a.w);
            o[4] = f2bf(bb.x); o[5] = f2bf(bb.y); o[6] = f2bf(bb.z); o[7] = f2bf(bb.w);
            *(uint4*)(xb + (size_t)i * 8) = *(uint4*)o;
        }
    } else if (b < NB_CAST5 + NB_TR5) {
        int tg = (b - NB_CAST5) * 512 + t;
        const int S1 = 128 * 256, S2 = 256 * 256, S3 = 256 * 64;
        if (tg < S1) transpose_one(W1, W1T, 128, 256, tg);
        else if (tg < S1 + S2) transpose_one(W2, W2T, 256, 256, tg - S1);
        else if (tg < S1 + S2 + S3) transpose_one(Wc, WcT, 256, 64, tg - S1 - S2);
    } else {
        // counting-sort this block's 4096 edges by bucket; compact private region
        __shared__ int lh[NBUCK];   // hist (kept)
        __shared__ int lb[NBUCK];   // exclusive offsets
        __shared__ int ws[512];     // scan buffer
        int blk = b - NB_CAST5 - NB_TR5;
        for (int i = t; i < NBUCK; i += 512) lh[i] = 0;
        __syncthreads();
        int base = blk * 4096;
        int s[8], bk[8], rk[8], lo[8];
#pragma unroll
        for (int k = 0; k < 8; ++k) {
            int e = base + k * 512 + t;
            bool ok = e < N_EDGES;
            int ee = ok ? e : 0;
            s[k] = ei[ee];
            int d = ei[N_EDGES + ee];
            bk[k] = ok ? (d >> 7) : -1;
            lo[k] = d & 127;
        }
#pragma unroll
        for (int k = 0; k < 8; ++k)
            if (bk[k] >= 0) rk[k] = atomicAdd(&lh[bk[k]], 1);
        __syncthreads();
        ws[t] = (t < NBUCK) ? lh[t] : 0;
        __syncthreads();
#pragma unroll
        for (int off = 1; off < 512; off <<= 1) {
            int u = (t >= off) ? ws[t - off] : 0;
            __syncthreads();
            ws[t] += u;
            __syncthreads();
        }
        if (t < NBUCK) lb[t] = ws[t] - lh[t];
        __syncthreads();
        for (int i = t; i < NBUCK; i += 512) {
            cnt[blk * NBUCK + i] = lh[i];
            ofs[blk * NBUCK + i] = lb[i];
        }
#pragma unroll
        for (int k = 0; k < 8; ++k)
            if (bk[k] >= 0)
                pbuf[base + lb[bk[k]] + rk[k]] = (unsigned)s[k] | ((unsigned)lo[k] << 17);
    }
}

// ---------------- bucket place: per-bucket segments -> nodestart/nodecnt + elist ----------------
__global__ __launch_bounds__(256) void k_bplace(const unsigned* __restrict__ pbuf,
                                                const int* __restrict__ cnt,
                                                const int* __restrict__ ofs,
                                                int* __restrict__ nodestart,
                                                int* __restrict__ nodecnt,
                                                int* __restrict__ elist) {
    __shared__ int segc[NB_SC], sego[NB_SC];
    __shared__ int lcnt[128], lexc[128], lcur[128];
    int b = blockIdx.x, t = threadIdx.x;
    for (int i = t; i < NB_SC; i += 256) {
        segc[i] = cnt[i * NBUCK + b];
        sego[i] = ofs[i * NBUCK + b];
    }
    if (t < 128) lcnt[t] = 0;
    __syncthreads();
    for (int i = t; i < NB_SC * MAXSEG; i += 256) {
        int blk = i >> 6, j = i & (MAXSEG - 1);
        if (j < segc[blk])
            atomicAdd(&lcnt[pbuf[blk * 4096 + sego[blk] + j] >> 17], 1);
    }
    __syncthreads();
    if (t < 128) lexc[t] = lcnt[t];
    __syncthreads();
#pragma unroll
    for (int off = 1; off < 128; off <<= 1) {
        int u = (t < 128 && t >= off) ? lexc[t - off] : 0;
        __syncthreads();
        if (t < 128) lexc[t] += u;
        __syncthreads();
    }
    if (t < 128) {
        int e = lexc[t] - lcnt[t];
        int node = (b << 7) + t;
        if (node < N_NODES) {
            nodestart[node] = b * EBMAX + e;
            nodecnt[node] = lcnt[t];
        }
        lcur[t] = e;
    }
    __syncthreads();
    for (int i = t; i < NB_SC * MAXSEG; i += 256) {
        int blk = i >> 6, j = i & (MAXSEG - 1);
        if (j < segc[blk]) {
            unsigned pr = pbuf[blk * 4096 + sego[blk] + j];
            int pos = atomicAdd(&lcur[pr >> 17], 1);
            elist[b * EBMAX + pos] = (int)(pr & 0x1FFFF);
        }
    }
}

// ---------------- fused gather + 3-stage MLP (R11-proven, 512 threads) ----------------
// 782 blocks x 512 threads (8 waves), 64-row stripe. LDS 80KB -> 2 blocks/CU.
__global__ __launch_bounds__(512) void k_fused(const ushort* __restrict__ xb,
                                               const int* __restrict__ nodestart,
                                               const int* __restrict__ nodecnt,
                                               const int* __restrict__ elist,
                                               const ushort* __restrict__ W1T,
                                               const float* __restrict__ b1,
                                               const ushort* __restrict__ W2T,
                                               const float* __restrict__ b2,
                                               const ushort* __restrict__ WcT,
                                               const float* __restrict__ bc,
                                               float* __restrict__ out, int M) {
    __shared__ ushort sA[2][64 * 64];
    __shared__ ushort sB[256 * 64];
    __shared__ ushort ht[64 * 256];

    int m0 = blockIdx.x * 64;
    int tid = threadIdx.x, wv = tid >> 6, lane = tid & 63;
    int lr = lane & 15;
    int kq = (lane >> 4) << 3;
    int l8 = (lane >> 3) & 7, c8 = lane & 7;
    int swz8 = c8 ^ l8;

    // issue W1T staging for BOTH kb halves up front
#pragma unroll
    for (int i = 0; i < 4; ++i) {
        int rg = wv * 32 + i * 8;
        gload16(W1T + (size_t)(rg + l8) * 128 + swz8 * 8, sB + rg * 64);
        gload16(W1T + (size_t)(rg + l8) * 128 + 64 + swz8 * 8, ht + rg * 64);
    }

    // ---- gather: 32 groups x 16 lanes, 2 nodes each; sums -> sA (bf16, swizzled) ----
    {
        int grp = tid >> 4, l16 = tid & 15;
        for (int nd = grp; nd < 64; nd += 32) {
            int node = m0 + nd;
            float a[8];
#pragma unroll
            for (int k = 0; k < 8; ++k) a[k] = 0.0f;
            if (node < N_NODES) {
                uint4 mine = *(const uint4*)(xb + (size_t)node * 128 + l16 * 8);
                const ushort* pm = (const ushort*)&mine;
#pragma unroll
                for (int k = 0; k < 8; ++k) a[k] = bf2f(pm[k]);
                int beg = nodestart[node], cnt = nodecnt[node];
                for (int base = 0; base < cnt; base += 16) {
                    int rem = cnt - base;
                    int idx = (l16 < rem) ? elist[beg + base + l16] : 0;
                    int c = rem < 16 ? rem : 16;
                    int j = 0;
                    for (; j + 8 <= c; j += 8) {   // 8 independent row loads in flight
                        uint4 v[8];
#pragma unroll
                        for (int u = 0; u < 8; ++u) {
                            int s = __shfl(idx, j + u, 16);
                            v[u] = *(const uint4*)(xb + (size_t)s * 128 + l16 * 8);
                        }
#pragma unroll
                        for (int u = 0; u < 8; ++u) {
                            const ushort* pv = (const ushort*)&v[u];
#pragma unroll
                            for (int k = 0; k < 8; ++k) a[k] += bf2f(pv[k]);
                        }
                    }
                    for (; j < c; ++j) {
                        int s = __shfl(idx, j, 16);
                        uint4 v = *(const uint4*)(xb + (size_t)s * 128 + l16 * 8);
                        const ushort* pv = (const ushort*)&v;
#pragma unroll
                        for (int k = 0; k < 8; ++k) a[k] += bf2f(pv[k]);
                    }
                }
            }
            ushort o[8];
#pragma unroll
            for (int k = 0; k < 8; ++k) o[k] = f2bf(a[k]);
            int h = l16 >> 3, cch = l16 & 7;
            *(uint4*)(&sA[h][nd * 64 + ((cch ^ (nd & 7)) << 3)]) = *(uint4*)o;
        }
    }
    __syncthreads();

    int wrow0 = (wv >> 2) * 32;   // stage1/2 wave grid: 2M(32 rows) x 4N(64 cols)
    int wcol0 = (wv & 3) * 64;
    int crow = (lane >> 4) << 2;

    f32x4 acc[2][4];

    // ======== stage 1: h1 = relu(hsum @ W1 + b1), K=128 (all operands resident) ========
#pragma unroll
    for (int m = 0; m < 2; ++m)
#pragma unroll
        for (int n = 0; n < 4; ++n) acc[m][n] = 0;

#pragma unroll
    for (int kbh = 0; kbh < 2; ++kbh) {
        const ushort* asrc = sA[kbh];
        const ushort* bsrc = kbh ? ht : sB;
#pragma unroll
        for (int kk = 0; kk < 64; kk += 32) {
            int cb = (kk + kq) * 2;
            bf16x8 af[2], bfr[4];
#pragma unroll
            for (int m = 0; m < 2; ++m) {
                int r = wrow0 + m * 16 + lr;
                af[m] = __builtin_bit_cast(bf16x8,
                    *(const uint4*)((const char*)asrc + r * 128 + (cb ^ ((r & 7) << 4))));
            }
#pragma unroll
            for (int n = 0; n < 4; ++n) {
                int r = wcol0 + n * 16 + lr;
                bfr[n] = __builtin_bit_cast(bf16x8,
                    *(const uint4*)((const char*)bsrc + r * 128 + (cb ^ ((r & 7) << 4))));
            }
#pragma unroll
            for (int m = 0; m < 2; ++m)
#pragma unroll
                for (int n = 0; n < 4; ++n)
                    acc[m][n] = __builtin_amdgcn_mfma_f32_16x16x32_bf16(
                        af[m], bfr[n], acc[m][n], 0, 0, 0);
        }
    }
    __syncthreads();   // all ht (W1T-kb64) reads done before overwrite

    // epilogue 1 -> ht (elem col c of row r stored at ((c>>3)^(r&7))<<3 | (c&7))
#pragma unroll
    for (int n = 0; n < 4; ++n) {
        int col = wcol0 + n * 16 + lr;
        float bv = b1[col];
#pragma unroll
        for (int m = 0; m < 2; ++m) {
#pragma unroll
            for (int r = 0; r < 4; ++r) {
                int row = wrow0 + m * 16 + crow + r;
                int sc = ((((col >> 3) ^ (row & 7)) << 3) | (col & 7));
                ht[row * 256 + sc] = f2bf(fmaxf(acc[m][n][r] + bv, 0.0f));
            }
        }
    }
    __syncthreads();

    // ======== stage 2: h2 = relu(h1 @ W2 + b2), K=256 ========
#pragma unroll
    for (int m = 0; m < 2; ++m)
#pragma unroll
        for (int n = 0; n < 4; ++n) acc[m][n] = 0;

    for (int kb = 0; kb < 256; kb += 64) {
#pragma unroll
        for (int i = 0; i < 4; ++i) {
            int rg = wv * 32 + i * 8;
            gload16(W2T + (size_t)(rg + l8) * 256 + kb + swz8 * 8, sB + rg * 64);
        }
        __syncthreads();
#pragma unroll
        for (int kk = 0; kk < 64; kk += 32) {
            int cc = kb + kk + kq;
            int cb = (kk + kq) * 2;
            bf16x8 af[2], bfr[4];
#pragma unroll
            for (int m = 0; m < 2; ++m) {
                int r = wrow0 + m * 16 + lr;
                af[m] = __builtin_bit_cast(bf16x8,
                    *(const uint4*)(ht + r * 256 + ((((cc >> 3) ^ (r & 7)) << 3))));
            }
#pragma unroll
            for (int n = 0; n < 4; ++n) {
                int r = wcol0 + n * 16 + lr;
                bfr[n] = __builtin_bit_cast(bf16x8,
                    *(const uint4*)((const char*)sB + r * 128 + (cb ^ ((r & 7) << 4))));
            }
#pragma unroll
            for (int m = 0; m < 2; ++m)
#pragma unroll
                for (int n = 0; n < 4; ++n)
                    acc[m][n] = __builtin_amdgcn_mfma_f32_16x16x32_bf16(
                        af[m], bfr[n], acc[m][n], 0, 0, 0);
        }
        __syncthreads();
    }
    // epilogue 2: overwrite ht with relu(h2); stage WcT (4 K-chunks) into sB
#pragma unroll
    for (int n = 0; n < 4; ++n) {
        int col = wcol0 + n * 16 + lr;
        float bv = b2[col];
#pragma unroll
        for (int m = 0; m < 2; ++m) {
#pragma unroll
            for (int r = 0; r < 4; ++r) {
                int row = wrow0 + m * 16 + crow + r;
                int sc = ((((col >> 3) ^ (row & 7)) << 3) | (col & 7));
                ht[row * 256 + sc] = f2bf(fmaxf(acc[m][n][r] + bv, 0.0f));
            }
        }
    }
#pragma unroll
    for (int i = 0; i < 4; ++i)
        gload16(WcT + (size_t)(wv * 8 + l8) * 256 + i * 64 + swz8 * 8,
                sB + i * 4096 + wv * 8 * 64);
    __syncthreads();

    // ======== stage 3: out = h2 @ Wc + bc, K=256; wave grid 4M(16 rows) x 2N(32 cols) ========
    f32x4 acc3[2];
#pragma unroll
    for (int n = 0; n < 2; ++n) acc3[n] = 0;
    int mrow0 = (wv & 3) * 16;
    int ncol0 = (wv >> 2) * 32;
    int arow3 = mrow0 + lr;
#pragma unroll
    for (int kb4 = 0; kb4 < 4; ++kb4) {
#pragma unroll
        for (int kk = 0; kk < 64; kk += 32) {
            int cc = kb4 * 64 + kk + kq;
            int cb = (kk + kq) * 2;
            bf16x8 a = __builtin_bit_cast(bf16x8,
                *(const uint4*)(ht + arow3 * 256 + ((((cc >> 3) ^ (arow3 & 7)) << 3))));
#pragma unroll
            for (int n = 0; n < 2; ++n) {
                int r = ncol0 + n * 16 + lr;
                bf16x8 b = __builtin_bit_cast(bf16x8,
                    *(const uint4*)((const char*)sB + kb4 * 8192 + r * 128 +
                                    (cb ^ ((r & 7) << 4))));
                acc3[n] = __builtin_amdgcn_mfma_f32_16x16x32_bf16(a, b, acc3[n], 0, 0, 0);
            }
        }
    }
#pragma unroll
    for (int n = 0; n < 2; ++n) {
        int col = ncol0 + n * 16 + lr;
        float bv = bc[col];
#pragma unroll
        for (int r = 0; r < 4; ++r) {
            int grow = m0 + mrow0 + crow + r;
            if (grow < M) out[(size_t)grow * 64 + col] = acc3[n][r] + bv;
        }
    }
}

// ---------------- launch ----------------

extern "C" void kernel_launch(void* const* d_in, const int* in_sizes, int n_in,
                              void* d_out, int out_size, void* d_ws, size_t ws_size,
                              hipStream_t stream) {
    const float* x  = (const float*)d_in[0];
    const int*   ei = (const int*)d_in[1];   // [2, 800000]: row0 = src, row1 = dst
    const float* W1 = (const float*)d_in[2];
    const float* b1 = (const float*)d_in[3];
    const float* W2 = (const float*)d_in[4];
    const float* b2 = (const float*)d_in[5];
    const float* Wc = (const float*)d_in[6];
    const float* bc = (const float*)d_in[7];
    float* out = (float*)d_out;

    char* p = (char*)d_ws;
    int* cnt         = (int*)p; p += NB_SC * NBUCK * 4;           // 306KB
    int* ofs         = (int*)p; p += NB_SC * NBUCK * 4;           // 306KB
    int* nodestart   = (int*)p; p += M_PAD * 4;
    int* nodecnt     = (int*)p; p += M_PAD * 4;
    unsigned* pbuf   = (unsigned*)p; p += (size_t)NB_SC * 4096 * 4;   // 3.2MB compact
    int* elist       = (int*)p; p += (size_t)NBUCK * EBMAX * 4;   // 6.4MB
    ushort* W1T = (ushort*)p; p += 256 * 128 * 2;
    ushort* W2T = (ushort*)p; p += 256 * 256 * 2;
    ushort* WcT = (ushort*)p; p += 64 * 256 * 2;
    ushort* xb  = (ushort*)p; p += (size_t)N_NODES * 128 * 2;

    k_prep<<<NB_CAST5 + NB_TR5 + NB_SC, 512, 0, stream>>>(x, xb, W1, W1T, W2, W2T,
                                                          Wc, WcT, ei, cnt, ofs, pbuf);
    k_bplace<<<NBUCK, 256, 0, stream>>>(pbuf, cnt, ofs, nodestart, nodecnt, elist);
    k_fused<<<M_PAD / 64, 512, 0, stream>>>(xb, nodestart, nodecnt, elist,
                                            W1T, b1, W2T, b2, WcT, bc, out, N_NODES);
}

// Round 14
// 96.145 us; speedup vs baseline: 1.2300x; 1.2300x over previous
//
#include <hip/hip_runtime.h>
#include <hip/hip_bf16.h>

#define N_NODES 50000
#define M_PAD   50048   // 782 * 64
#define N_EDGES 800000
#define NBUCK   391     // bucket = dst>>7 -> 128 nodes per bucket
#define NB_EB8  196     // ceil(800000/4096)
#define NB_CAST 3125    // 50000*128/8/256
#define NB_TR   448     // (128*256+256*256+256*64)/256
#define EBMAX   4096    // fixed per-bucket capacity (actual max ~2300)

typedef __bf16 bf16x8 __attribute__((ext_vector_type(8)));
typedef float  f32x4  __attribute__((ext_vector_type(4)));

__device__ __forceinline__ ushort f2bf(float f) {
    __hip_bfloat16 h = __float2bfloat16(f);
    return __builtin_bit_cast(ushort, h);
}
__device__ __forceinline__ float bf2f(ushort u) {
    return __builtin_bit_cast(float, (unsigned)u << 16);
}

// async global->LDS, 16B per lane; lds base must be wave-uniform
__device__ __forceinline__ void gload16(const ushort* g, ushort* l) {
    __builtin_amdgcn_global_load_lds(
        (const __attribute__((address_space(1))) unsigned*)g,
        (__attribute__((address_space(3))) unsigned*)l, 16, 0, 0);
}

// ---------------- prep: x cast + weight transpose + cursor zeroing ----------------
__device__ __forceinline__ void transpose_one(const float* W, ushort* WT,
                                              int K, int N, int t) {
    int k = t / N, n = t % N;
    WT[n * K + k] = f2bf(W[t]);
}

__global__ __launch_bounds__(256) void k_prep(const float* __restrict__ x,
                                              ushort* __restrict__ xb,
                                              const float* __restrict__ W1, ushort* __restrict__ W1T,
                                              const float* __restrict__ W2, ushort* __restrict__ W2T,
                                              const float* __restrict__ Wc, ushort* __restrict__ WcT,
                                              int* __restrict__ bcur) {
    int b = blockIdx.x, t = threadIdx.x;
    if (b < NB_CAST) {
        int i = b * 256 + t;  // 8 elems each
        const float4* x4 = (const float4*)x;
        float4 a = x4[(size_t)i * 2], bb = x4[(size_t)i * 2 + 1];
        ushort o[8];
        o[0] = f2bf(a.x); o[1] = f2bf(a.y); o[2] = f2bf(a.z); o[3] = f2bf(a.w);
        o[4] = f2bf(bb.x); o[5] = f2bf(bb.y); o[6] = f2bf(bb.z); o[7] = f2bf(bb.w);
        *(uint4*)(xb + (size_t)i * 8) = *(uint4*)o;
    } else if (b < NB_CAST + NB_TR) {
        int tg = (b - NB_CAST) * 256 + t;
        const int S1 = 128 * 256, S2 = 256 * 256, S3 = 256 * 64;
        if (tg < S1) transpose_one(W1, W1T, 128, 256, tg);
        else if (tg < S1 + S2) transpose_one(W2, W2T, 256, 256, tg - S1);
        else if (tg < S1 + S2 + S3) transpose_one(Wc, WcT, 256, 64, tg - S1 - S2);
    } else {
        for (int i = t; i < 400; i += 256) bcur[i] = 0;
    }
}

// ---------------- bucket scatter: fixed-capacity regions, ILP-8 ----------------
// pbuf[bk*EBMAX + pos] = src | ((dst&127)<<17). Final bcur[bk] = bucket count.
__global__ __launch_bounds__(512) void k_bscatter(const int* __restrict__ ei,
                                                  int* __restrict__ bcur,
                                                  unsigned* __restrict__ pbuf) {
    __shared__ int lh[NBUCK];
    __shared__ int lbase[NBUCK];
    int t = threadIdx.x;
    for (int i = t; i < NBUCK; i += 512) lh[i] = 0;
    __syncthreads();
    int base = blockIdx.x * 4096 + t;
    int s[8], bk[8], rk[8], lo[8];
#pragma unroll
    for (int k = 0; k < 8; ++k) {
        int e = base + k * 512;
        bool ok = e < N_EDGES;
        int ee = ok ? e : 0;
        s[k] = ei[ee];
        int d = ei[N_EDGES + ee];
        bk[k] = ok ? (d >> 7) : -1;
        lo[k] = d & 127;
    }
#pragma unroll
    for (int k = 0; k < 8; ++k)
        if (bk[k] >= 0) rk[k] = atomicAdd(&lh[bk[k]], 1);
    __syncthreads();
    for (int i = t; i < NBUCK; i += 512) {
        int v = lh[i];
        lbase[i] = v ? atomicAdd(&bcur[i], v) : 0;
    }
    __syncthreads();
#pragma unroll
    for (int k = 0; k < 8; ++k)
        if (bk[k] >= 0) {
            int pos = lbase[bk[k]] + rk[k];
            if (pos < EBMAX)
                pbuf[bk[k] * EBMAX + pos] = (unsigned)s[k] | ((unsigned)lo[k] << 17);
        }
}

// ---------------- bucket place: per-node LDS count/scan -> nodestart/nodecnt + elist ----------------
__global__ __launch_bounds__(256) void k_bplace(const unsigned* __restrict__ pbuf,
                                                const int* __restrict__ bcur,
                                                int* __restrict__ nodestart,
                                                int* __restrict__ nodecnt,
                                                int* __restrict__ elist) {
    __shared__ int lcnt[128], lexc[128], lcur[128];
    int b = blockIdx.x, t = threadIdx.x;
    int m = bcur[b]; if (m > EBMAX) m = EBMAX;
    const unsigned* pb = pbuf + b * EBMAX;
    if (t < 128) lcnt[t] = 0;
    __syncthreads();
    for (int i = t; i < m; i += 256)
        atomicAdd(&lcnt[pb[i] >> 17], 1);
    __syncthreads();
    if (t < 128) lexc[t] = lcnt[t];
    __syncthreads();
#pragma unroll
    for (int off = 1; off < 128; off <<= 1) {
        int u = (t < 128 && t >= off) ? lexc[t - off] : 0;
        __syncthreads();
        if (t < 128) lexc[t] += u;
        __syncthreads();
    }
    if (t < 128) {
        int e = lexc[t] - lcnt[t];
        int node = (b << 7) + t;
        if (node < N_NODES) {
            nodestart[node] = b * EBMAX + e;
            nodecnt[node] = lcnt[t];
        }
        lcur[t] = e;
    }
    __syncthreads();
    for (int i = t; i < m; i += 256) {
        unsigned pr = pb[i];
        int pos = atomicAdd(&lcur[pr >> 17], 1);
        elist[b * EBMAX + pos] = (int)(pr & 0x1FFFF);
    }
}

// ---------------- fused gather + 3-stage MLP (R11-proven, 512 threads) ----------------
// 782 blocks x 512 threads (8 waves), 64-row stripe. LDS 80KB -> 2 blocks/CU.
__global__ __launch_bounds__(512) void k_fused(const ushort* __restrict__ xb,
                                               const int* __restrict__ nodestart,
                                               const int* __restrict__ nodecnt,
                                               const int* __restrict__ elist,
                                               const ushort* __restrict__ W1T,
                                               const float* __restrict__ b1,
                                               const ushort* __restrict__ W2T,
                                               const float* __restrict__ b2,
                                               const ushort* __restrict__ WcT,
                                               const float* __restrict__ bc,
                                               float* __restrict__ out, int M) {
    __shared__ ushort sA[2][64 * 64];
    __shared__ ushort sB[256 * 64];
    __shared__ ushort ht[64 * 256];

    int m0 = blockIdx.x * 64;
    int tid = threadIdx.x, wv = tid >> 6, lane = tid & 63;
    int lr = lane & 15;
    int kq = (lane >> 4) << 3;
    int l8 = (lane >> 3) & 7, c8 = lane & 7;
    int swz8 = c8 ^ l8;

    // issue W1T staging for BOTH kb halves up front
#pragma unroll
    for (int i = 0; i < 4; ++i) {
        int rg = wv * 32 + i * 8;
        gload16(W1T + (size_t)(rg + l8) * 128 + swz8 * 8, sB + rg * 64);
        gload16(W1T + (size_t)(rg + l8) * 128 + 64 + swz8 * 8, ht + rg * 64);
    }

    // ---- gather: 32 groups x 16 lanes, 2 nodes each; sums -> sA (bf16, swizzled) ----
    {
        int grp = tid >> 4, l16 = tid & 15;
        for (int nd = grp; nd < 64; nd += 32) {
            int node = m0 + nd;
            float a[8];
#pragma unroll
            for (int k = 0; k < 8; ++k) a[k] = 0.0f;
            if (node < N_NODES) {
                uint4 mine = *(const uint4*)(xb + (size_t)node * 128 + l16 * 8);
                const ushort* pm = (const ushort*)&mine;
#pragma unroll
                for (int k = 0; k < 8; ++k) a[k] = bf2f(pm[k]);
                int beg = nodestart[node], cnt = nodecnt[node];
                for (int base = 0; base < cnt; base += 16) {
                    int rem = cnt - base;
                    int idx = (l16 < rem) ? elist[beg + base + l16] : 0;
                    int c = rem < 16 ? rem : 16;
                    int j = 0;
                    for (; j + 8 <= c; j += 8) {   // 8 independent row loads in flight
                        uint4 v[8];
#pragma unroll
                        for (int u = 0; u < 8; ++u) {
                            int s = __shfl(idx, j + u, 16);
                            v[u] = *(const uint4*)(xb + (size_t)s * 128 + l16 * 8);
                        }
#pragma unroll
                        for (int u = 0; u < 8; ++u) {
                            const ushort* pv = (const ushort*)&v[u];
#pragma unroll
                            for (int k = 0; k < 8; ++k) a[k] += bf2f(pv[k]);
                        }
                    }
                    for (; j < c; ++j) {
                        int s = __shfl(idx, j, 16);
                        uint4 v = *(const uint4*)(xb + (size_t)s * 128 + l16 * 8);
                        const ushort* pv = (const ushort*)&v;
#pragma unroll
                        for (int k = 0; k < 8; ++k) a[k] += bf2f(pv[k]);
                    }
                }
            }
            ushort o[8];
#pragma unroll
            for (int k = 0; k < 8; ++k) o[k] = f2bf(a[k]);
            int h = l16 >> 3, cch = l16 & 7;
            *(uint4*)(&sA[h][nd * 64 + ((cch ^ (nd & 7)) << 3)]) = *(uint4*)o;
        }
    }
    __syncthreads();

    int wrow0 = (wv >> 2) * 32;   // stage1/2 wave grid: 2M(32 rows) x 4N(64 cols)
    int wcol0 = (wv & 3) * 64;
    int crow = (lane >> 4) << 2;

    f32x4 acc[2][4];

    // ======== stage 1: h1 = relu(hsum @ W1 + b1), K=128 (all operands resident) ========
#pragma unroll
    for (int m = 0; m < 2; ++m)
#pragma unroll
        for (int n = 0; n < 4; ++n) acc[m][n] = 0;

#pragma unroll
    for (int kbh = 0; kbh < 2; ++kbh) {
        const ushort* asrc = sA[kbh];
        const ushort* bsrc = kbh ? ht : sB;
#pragma unroll
        for (int kk = 0; kk < 64; kk += 32) {
            int cb = (kk + kq) * 2;
            bf16x8 af[2], bfr[4];
#pragma unroll
            for (int m = 0; m < 2; ++m) {
                int r = wrow0 + m * 16 + lr;
                af[m] = __builtin_bit_cast(bf16x8,
                    *(const uint4*)((const char*)asrc + r * 128 + (cb ^ ((r & 7) << 4))));
            }
#pragma unroll
            for (int n = 0; n < 4; ++n) {
                int r = wcol0 + n * 16 + lr;
                bfr[n] = __builtin_bit_cast(bf16x8,
                    *(const uint4*)((const char*)bsrc + r * 128 + (cb ^ ((r & 7) << 4))));
            }
#pragma unroll
            for (int m = 0; m < 2; ++m)
#pragma unroll
                for (int n = 0; n < 4; ++n)
                    acc[m][n] = __builtin_amdgcn_mfma_f32_16x16x32_bf16(
                        af[m], bfr[n], acc[m][n], 0, 0, 0);
        }
    }
    __syncthreads();   // all ht (W1T-kb64) reads done before overwrite

    // epilogue 1 -> ht (elem col c of row r stored at ((c>>3)^(r&7))<<3 | (c&7))
#pragma unroll
    for (int n = 0; n < 4; ++n) {
        int col = wcol0 + n * 16 + lr;
        float bv = b1[col];
#pragma unroll
        for (int m = 0; m < 2; ++m) {
#pragma unroll
            for (int r = 0; r < 4; ++r) {
                int row = wrow0 + m * 16 + crow + r;
                int sc = ((((col >> 3) ^ (row & 7)) << 3) | (col & 7));
                ht[row * 256 + sc] = f2bf(fmaxf(acc[m][n][r] + bv, 0.0f));
            }
        }
    }
    __syncthreads();

    // ======== stage 2: h2 = relu(h1 @ W2 + b2), K=256 ========
#pragma unroll
    for (int m = 0; m < 2; ++m)
#pragma unroll
        for (int n = 0; n < 4; ++n) acc[m][n] = 0;

    for (int kb = 0; kb < 256; kb += 64) {
#pragma unroll
        for (int i = 0; i < 4; ++i) {
            int rg = wv * 32 + i * 8;
            gload16(W2T + (size_t)(rg + l8) * 256 + kb + swz8 * 8, sB + rg * 64);
        }
        __syncthreads();
#pragma unroll
        for (int kk = 0; kk < 64; kk += 32) {
            int cc = kb + kk + kq;
            int cb = (kk + kq) * 2;
            bf16x8 af[2], bfr[4];
#pragma unroll
            for (int m = 0; m < 2; ++m) {
                int r = wrow0 + m * 16 + lr;
                af[m] = __builtin_bit_cast(bf16x8,
                    *(const uint4*)(ht + r * 256 + ((((cc >> 3) ^ (r & 7)) << 3))));
            }
#pragma unroll
            for (int n = 0; n < 4; ++n) {
                int r = wcol0 + n * 16 + lr;
                bfr[n] = __builtin_bit_cast(bf16x8,
                    *(const uint4*)((const char*)sB + r * 128 + (cb ^ ((r & 7) << 4))));
            }
#pragma unroll
            for (int m = 0; m < 2; ++m)
#pragma unroll
                for (int n = 0; n < 4; ++n)
                    acc[m][n] = __builtin_amdgcn_mfma_f32_16x16x32_bf16(
                        af[m], bfr[n], acc[m][n], 0, 0, 0);
        }
        __syncthreads();
    }
    // epilogue 2: overwrite ht with relu(h2); stage WcT (4 K-chunks) into sB
#pragma unroll
    for (int n = 0; n < 4; ++n) {
        int col = wcol0 + n * 16 + lr;
        float bv = b2[col];
#pragma unroll
        for (int m = 0; m < 2; ++m) {
#pragma unroll
            for (int r = 0; r < 4; ++r) {
                int row = wrow0 + m * 16 + crow + r;
                int sc = ((((col >> 3) ^ (row & 7)) << 3) | (col & 7));
                ht[row * 256 + sc] = f2bf(fmaxf(acc[m][n][r] + bv, 0.0f));
            }
        }
    }
#pragma unroll
    for (int i = 0; i < 4; ++i)
        gload16(WcT + (size_t)(wv * 8 + l8) * 256 + i * 64 + swz8 * 8,
                sB + i * 4096 + wv * 8 * 64);
    __syncthreads();

    // ======== stage 3: out = h2 @ Wc + bc, K=256; wave grid 4M(16 rows) x 2N(32 cols) ========
    f32x4 acc3[2];
#pragma unroll
    for (int n = 0; n < 2; ++n) acc3[n] = 0;
    int mrow0 = (wv & 3) * 16;
    int ncol0 = (wv >> 2) * 32;
    int arow3 = mrow0 + lr;
#pragma unroll
    for (int kb4 = 0; kb4 < 4; ++kb4) {
#pragma unroll
        for (int kk = 0; kk < 64; kk += 32) {
            int cc = kb4 * 64 + kk + kq;
            int cb = (kk + kq) * 2;
            bf16x8 a = __builtin_bit_cast(bf16x8,
                *(const uint4*)(ht + arow3 * 256 + ((((cc >> 3) ^ (arow3 & 7)) << 3))));
#pragma unroll
            for (int n = 0; n < 2; ++n) {
                int r = ncol0 + n * 16 + lr;
                bf16x8 b = __builtin_bit_cast(bf16x8,
                    *(const uint4*)((const char*)sB + kb4 * 8192 + r * 128 +
                                    (cb ^ ((r & 7) << 4))));
                acc3[n] = __builtin_amdgcn_mfma_f32_16x16x32_bf16(a, b, acc3[n], 0, 0, 0);
            }
        }
    }
#pragma unroll
    for (int n = 0; n < 2; ++n) {
        int col = ncol0 + n * 16 + lr;
        float bv = bc[col];
#pragma unroll
        for (int r = 0; r < 4; ++r) {
            int grow = m0 + mrow0 + crow + r;
            if (grow < M) out[(size_t)grow * 64 + col] = acc3[n][r] + bv;
        }
    }
}

// ---------------- launch ----------------

extern "C" void kernel_launch(void* const* d_in, const int* in_sizes, int n_in,
                              void* d_out, int out_size, void* d_ws, size_t ws_size,
                              hipStream_t stream) {
    const float* x  = (const float*)d_in[0];
    const int*   ei = (const int*)d_in[1];   // [2, 800000]: row0 = src, row1 = dst
    const float* W1 = (const float*)d_in[2];
    const float* b1 = (const float*)d_in[3];
    const float* W2 = (const float*)d_in[4];
    const float* b2 = (const float*)d_in[5];
    const float* Wc = (const float*)d_in[6];
    const float* bc = (const float*)d_in[7];
    float* out = (float*)d_out;

    char* p = (char*)d_ws;
    int* bcur        = (int*)p; p += 400 * 4;
    int* nodestart   = (int*)p; p += M_PAD * 4;
    int* nodecnt     = (int*)p; p += M_PAD * 4;
    unsigned* pbuf   = (unsigned*)p; p += (size_t)NBUCK * EBMAX * 4;
    int* elist       = (int*)p; p += (size_t)NBUCK * EBMAX * 4;
    ushort* W1T = (ushort*)p; p += 256 * 128 * 2;
    ushort* W2T = (ushort*)p; p += 256 * 256 * 2;
    ushort* WcT = (ushort*)p; p += 64 * 256 * 2;
    ushort* xb  = (ushort*)p; p += (size_t)N_NODES * 128 * 2;

    k_prep<<<NB_CAST + NB_TR + 1, 256, 0, stream>>>(x, xb, W1, W1T, W2, W2T, Wc, WcT, bcur);
    k_bscatter<<<NB_EB8, 512, 0, stream>>>(ei, bcur, pbuf);
    k_bplace<<<NBUCK, 256, 0, stream>>>(pbuf, bcur, nodestart, nodecnt, elist);
    k_fused<<<M_PAD / 64, 512, 0, stream>>>(xb, nodestart, nodecnt, elist,
                                            W1T, b1, W2T, b2, WcT, bc, out, N_NODES);
}